// Round 5
// baseline (358.158 us; speedup 1.0000x reference)
//
#include <hip/hip_runtime.h>
#include <hip/hip_bf16.h>

#define HID 64
#define HEADS 4

typedef short s16x8 __attribute__((ext_vector_type(8)));   // 8 bf16 (4 VGPRs)
typedef short s16x4 __attribute__((ext_vector_type(4)));
typedef float f32x4 __attribute__((ext_vector_type(4)));
typedef float f32x2 __attribute__((ext_vector_type(2)));   // lowers to v_pk_*_f32

// flag convention: *flag >= 8  =>  float inputs are fp32; else bf16.
__device__ __forceinline__ float ldw(const void* p, long i, bool f32) {
    return f32 ? ((const float*)p)[i] : (float)((const __hip_bfloat16*)p)[i];
}

__device__ __forceinline__ unsigned short f2b(float f) {   // fp32 -> bf16 bits (RNE, finite)
    unsigned int u = __builtin_bit_cast(unsigned int, f);
    u += 0x7FFF + ((u >> 16) & 1);
    return (unsigned short)(u >> 16);
}
__device__ __forceinline__ float b2f(unsigned short s) {
    unsigned int u = ((unsigned int)s) << 16;
    return __builtin_bit_cast(float, u);
}

// ---------------- dtype probe (16 blocks, coalesced) ----------------
__global__ void detect_kernel(const unsigned short* __restrict__ p, int* __restrict__ flag) {
    int gtid = blockIdx.x * 256 + threadIdx.x;   // 4096 threads x 8 words = 32768
    int hits = 0;
    #pragma unroll
    for (int k = 0; k < 8; k++) {
        unsigned short v = p[gtid + k * 4096];
        if (((v >> 7) & 0xFF) == 0xFF) hits++;   // bf16 NaN/Inf exponent pattern
    }
    if (hits) atomicAdd(flag, hits);
}

// ---------------- prep: A (activations/nodes) -> bf16 hi/lo planes ----------------
__global__ void prep_a(const void* __restrict__ src, const int* __restrict__ flag,
                       unsigned short* __restrict__ hi, unsigned short* __restrict__ lo,
                       long n) {
    const bool f32 = (*flag >= 8);
    long i = (long)blockIdx.x * 1024 + (long)threadIdx.x * 4;
    if (i >= n) return;
    s16x4 vh, vl;
    if (f32) {
        f32x4 v = *(const f32x4*)((const float*)src + i);
        #pragma unroll
        for (int j = 0; j < 4; j++) {
            unsigned short hb = f2b(v[j]);
            vh[j] = (short)hb;
            vl[j] = (short)f2b(v[j] - b2f(hb));
        }
    } else {
        vh = *(const s16x4*)((const unsigned short*)src + i);
        vl = (s16x4){0, 0, 0, 0};
    }
    *(s16x4*)(hi + i) = vh;
    *(s16x4*)(lo + i) = vl;
}

// ---------------- prep: W [K,64] -> W^T bf16 [64,K] ----------------
__global__ void prep_w(const void* __restrict__ W, const int* __restrict__ flag,
                       unsigned short* __restrict__ Wt, int K) {
    const bool f32 = (*flag >= 8);
    int i = blockIdx.x * 256 + threadIdx.x;
    if (i < K * 64) {
        int k = i >> 6, n = i & 63;
        Wt[n * K + k] = f2b(ldw(W, i, f32));
    }
}

// ---------------- CSR build ----------------

__global__ void hist_kernel(const int* __restrict__ recv, int* __restrict__ cnt, int E) {
    int i = blockIdx.x * blockDim.x + threadIdx.x;
    if (i < E) atomicAdd(&cnt[recv[i]], 1);
}

__global__ __launch_bounds__(1024) void scan_kernel(const int* __restrict__ cnt,
                                                    int* __restrict__ off,
                                                    int* __restrict__ cursor, int n) {
    const int C = (n + 1023) >> 10;          // assume <= 32
    int tid = threadIdx.x;
    int base = tid * C;
    int v[32];
    int tot = 0;
    for (int j = 0; j < C; j++) {
        int idx = base + j;
        int x = (idx < n) ? cnt[idx] : 0;
        v[j] = tot;
        tot += x;
    }
    int lane = tid & 63, w = tid >> 6;
    int incl = tot;
    #pragma unroll
    for (int s = 1; s < 64; s <<= 1) {
        int t = __shfl_up(incl, s, 64);
        if (lane >= s) incl += t;
    }
    __shared__ int wsum[16];
    __shared__ int woff[16];
    if (lane == 63) wsum[w] = incl;
    __syncthreads();
    if (tid < 16) {
        int s = 0;
        for (int i = 0; i < tid; i++) s += wsum[i];
        woff[tid] = s;
    }
    __syncthreads();
    int toff = woff[w] + (incl - tot);
    for (int j = 0; j < C; j++) {
        int idx = base + j;
        if (idx < n) { off[idx] = toff + v[j]; cursor[idx] = toff + v[j]; }
    }
    if (tid == 1023) off[n] = toff + tot;
}

__global__ void scatter_kernel(const int* __restrict__ recv, const int* __restrict__ send,
                               int* __restrict__ cursor, int* __restrict__ ssorted, int E) {
    int i = blockIdx.x * blockDim.x + threadIdx.x;
    if (i < E) {
        int pos = atomicAdd(&cursor[recv[i]], 1);
        ssorted[pos] = send[i];
    }
}

// ---------------- MFMA GEMM: h = A @ W + b,  A = Ah + Al (bf16 planes) ----------------

template <int K>
__global__ __launch_bounds__(256) void gemm_mfma(const unsigned short* __restrict__ Ah,
                                                 const unsigned short* __restrict__ Al,
                                                 const unsigned short* __restrict__ Wt,
                                                 const void* __restrict__ bq,
                                                 const int* __restrict__ flag,
                                                 float* __restrict__ h, int M, int lo_always) {
    const bool f32 = (*flag >= 8);
    const bool use_lo = lo_always || f32;
    int lane = threadIdx.x & 63, wv = threadIdx.x >> 6;
    int m16 = lane & 15, quad = lane >> 4;

    int tiles = (M + 15) >> 4;
    int tile = blockIdx.x * 4 + wv;
    if (tile >= tiles) return;

    float bias[4];
    #pragma unroll
    for (int t = 0; t < 4; t++) bias[t] = ldw(bq, 16 * t + m16, f32);

    int m0 = tile << 4;
    int row = m0 + m16;
    bool rv = row < M;
    long abase = (long)row * K;
    f32x4 acc[4] = {{0.f,0.f,0.f,0.f},{0.f,0.f,0.f,0.f},{0.f,0.f,0.f,0.f},{0.f,0.f,0.f,0.f}};

    #pragma unroll
    for (int ks = 0; ks < K / 32; ks++) {
        int kb = ks * 32 + quad * 8;
        s16x8 b[4];
        #pragma unroll
        for (int t = 0; t < 4; t++)
            b[t] = *(const s16x8*)(Wt + (16 * t + m16) * K + kb);
        s16x8 ah = rv ? *(const s16x8*)(Ah + abase + kb) : (s16x8){0,0,0,0,0,0,0,0};
        #pragma unroll
        for (int t = 0; t < 4; t++)
            acc[t] = __builtin_amdgcn_mfma_f32_16x16x32_bf16(ah, b[t], acc[t], 0, 0, 0);
        if (use_lo) {
            s16x8 al = rv ? *(const s16x8*)(Al + abase + kb) : (s16x8){0,0,0,0,0,0,0,0};
            #pragma unroll
            for (int t = 0; t < 4; t++)
                acc[t] = __builtin_amdgcn_mfma_f32_16x16x32_bf16(al, b[t], acc[t], 0, 0, 0);
        }
    }

    #pragma unroll
    for (int t = 0; t < 4; t++) {
        #pragma unroll
        for (int r = 0; r < 4; r++) {
            int orow = m0 + quad * 4 + r;        // C/D: col=lane&15, row=quad*4+reg
            if (orow < M) h[(long)orow * 64 + 16 * t + m16] = acc[t][r] + bias[t];
        }
    }
}

// ---------------- Attention: packed-fp32 segment softmax + aggregate ----------------
// One wave per receiver. half-wave 0 -> even edges, half-wave 1 -> odd edges of the
// SAME receiver (no divergence). Each lane owns 2 hidden dims as float2 so per-head
// math lowers to v_pk_*_f32 (full-rate 2-wide fp32). Partials merged by shfl_xor(32).
// Numerics: logits ~ O(1) (verified R3/R4: absmax = 1 bf16 ulp), so no-max softmax
// is safe; log2(e) folded into weights (leaky(z)*c == leaky(z*c), c>0) -> raw exp2.

__global__ __launch_bounds__(256) void attn_kernel(
    const float* __restrict__ h, const int* __restrict__ off,
    const int* __restrict__ ssorted,
    const void* __restrict__ Wl, const void* __restrict__ bl,
    const int* __restrict__ flag,
    unsigned short* __restrict__ xh, unsigned short* __restrict__ xl,
    void* __restrict__ out, int n, int last) {
    const bool f32 = (*flag >= 8);
    int lane = threadIdx.x & 63;
    int half = lane >> 5;                    // 0: even edges, 1: odd edges
    int hl = lane & 31;                      // dims 2*hl, 2*hl+1
    int r = __builtin_amdgcn_readfirstlane(blockIdx.x * 4 + (threadIdx.x >> 6));
    if (r >= n) return;

    const float LOG2E = 1.44269504f;
    f32x2 hr2 = *(const f32x2*)(h + (long)r * HID + 2 * hl);
    float w0[HEADS];
    f32x2 c2[HEADS];
    #pragma unroll
    for (int k = 0; k < HEADS; k++) {
        w0[k] = ldw(Wl, k, f32) * LOG2E;
        float w1 = ldw(Wl, HEADS + k, f32) * LOG2E;
        float bb = ldw(bl, k, f32) * LOG2E;
        c2[k].x = fmaf(hr2.x, w1, bb);       // receiver part: loop-invariant
        c2[k].y = fmaf(hr2.y, w1, bb);
    }

    f32x2 l2[HEADS], a2[HEADS];
    #pragma unroll
    for (int k = 0; k < HEADS; k++) { l2[k] = (f32x2){0.f, 0.f}; a2[k] = (f32x2){0.f, 0.f}; }

    int start = off[r], end = off[r + 1];    // scalar (r wave-uniform)
    int len = end - start;
    int pairs = len >> 1;

    int e = start + half;
    int s = (pairs > 0) ? ssorted[e] : 0;    // both halves valid when >=1 full pair
    f32x2 hs2 = (pairs > 0) ? *(const f32x2*)(h + (long)s * HID + 2 * hl)
                            : (f32x2){0.f, 0.f};
    for (int j = 0; j < pairs; j++) {
        f32x2 hcur = hs2;
        int enext = e + 2;
        if (j + 1 < pairs) {                 // pipeline next pair's row
            int sn = ssorted[enext];
            hs2 = *(const f32x2*)(h + (long)sn * HID + 2 * hl);
        }
        e = enext;
        #pragma unroll
        for (int k = 0; k < HEADS; k++) {
            f32x2 t = hcur * w0[k] + c2[k];  // pk_fma
            f32x2 t2 = t * 0.2f;             // pk_mul
            t = (f32x2){fmaxf(t.x, t2.x), fmaxf(t.y, t2.y)};   // pk_max (leaky, log2-dom)
            f32x2 p = (f32x2){exp2f(t.x), exp2f(t.y)};
            l2[k] += p;                      // pk_add
            a2[k] += p * hcur;               // pk_fma
        }
    }
    if (len & 1) {                           // tail: lone edge on half 0, half 1 masked
        int et = end - 1;
        int st = ssorted[et];
        f32x2 ht = *(const f32x2*)(h + (long)st * HID + 2 * hl);
        float msk = (half == 0) ? 1.f : 0.f;
        #pragma unroll
        for (int k = 0; k < HEADS; k++) {
            f32x2 t = ht * w0[k] + c2[k];
            f32x2 t2 = t * 0.2f;
            t = (f32x2){fmaxf(t.x, t2.x), fmaxf(t.y, t2.y)};
            f32x2 p = (f32x2){exp2f(t.x) * msk, exp2f(t.y) * msk};
            l2[k] += p;
            a2[k] += p * ht;
        }
    }

    // merge half-wave partials (lane i and lane i+32 hold same dims)
    #pragma unroll
    for (int k = 0; k < HEADS; k++) {
        l2[k].x += __shfl_xor(l2[k].x, 32, 64);
        l2[k].y += __shfl_xor(l2[k].y, 32, 64);
        a2[k].x += __shfl_xor(a2[k].x, 32, 64);
        a2[k].y += __shfl_xor(a2[k].y, 32, 64);
    }
    if (half != 0) return;                   // lanes 0-31 write results

    bool has = (len > 0);
    if (!last) {
        float v[8];                          // dims 2hl, 2hl+1 x 4 heads
        #pragma unroll
        for (int k = 0; k < HEADS; k++) {
            float ax = has ? a2[k].x / l2[k].x : 0.f;
            float ay = has ? a2[k].y / l2[k].y : 0.f;
            v[k]     = (ax > 0.f) ? ax : (__expf(ax) - 1.f);   // elu
            v[4 + k] = (ay > 0.f) ? ay : (__expf(ay) - 1.f);
        }
        s16x8 vh, vlo;                       // layout d*HEADS+k: [d0 k0..3, d1 k0..3]
        #pragma unroll
        for (int k = 0; k < 4; k++) {
            unsigned short hb = f2b(v[k]);
            vh[k] = (short)hb;  vlo[k] = (short)f2b(v[k] - b2f(hb));
            unsigned short hb2 = f2b(v[4 + k]);
            vh[4 + k] = (short)hb2;  vlo[4 + k] = (short)f2b(v[4 + k] - b2f(hb2));
        }
        long o = (long)r * (HID * HEADS) + 8 * hl;
        *(s16x8*)(xh + o) = vh;
        *(s16x8*)(xl + o) = vlo;
    } else {
        float sx = 0.f, sy = 0.f;
        #pragma unroll
        for (int k = 0; k < HEADS; k++) {
            sx += has ? a2[k].x / l2[k].x : 0.f;
            sy += has ? a2[k].y / l2[k].y : 0.f;
        }
        float ax = sx * 0.25f, ay = sy * 0.25f;            // mean over heads
        ax = (ax > 0.f) ? ax : (__expf(ax) - 1.f);         // elu
        ay = (ay > 0.f) ? ay : (__expf(ay) - 1.f);
        long o = (long)r * HID + 2 * hl;
        if (f32) {
            *(f32x2*)((float*)out + o) = (f32x2){ax, ay};
        } else {
            unsigned int pk = (unsigned int)f2b(ax) | ((unsigned int)f2b(ay) << 16);
            *(unsigned int*)((unsigned short*)out + o) = pk;
        }
    }
}

// ---------------- launch ----------------

extern "C" void kernel_launch(void* const* d_in, const int* in_sizes, int n_in,
                              void* d_out, int out_size, void* d_ws, size_t ws_size,
                              hipStream_t stream) {
    const void* nodes    = d_in[0];
    const int* senders   = (const int*)d_in[1];
    const int* receivers = (const int*)d_in[2];
    const void* Wq0 = d_in[3];  const void* bq0 = d_in[4];
    const void* Wl0 = d_in[5];  const void* bl0 = d_in[6];
    const void* Wq1 = d_in[7];  const void* bq1 = d_in[8];
    const void* Wl1 = d_in[9];  const void* bl1 = d_in[10];
    const void* Wq2 = d_in[11]; const void* bq2 = d_in[12];
    const void* Wl2 = d_in[13]; const void* bl2 = d_in[14];

    int N = in_sizes[0] / 128;
    int E = in_sizes[1];

    char* p = (char*)d_ws;
    int* flag = (int*)p;            p += 64;
    float* h = (float*)p;           p += (size_t)N * 64 * 4;            // 6.4 MB
    unsigned short* nh = (unsigned short*)p;  p += (size_t)N * 128 * 2; // 6.4 MB
    unsigned short* nl = (unsigned short*)p;  p += (size_t)N * 128 * 2;
    unsigned short* xh = (unsigned short*)p;  p += (size_t)N * 256 * 2; // 12.8 MB
    unsigned short* xl = (unsigned short*)p;  p += (size_t)N * 256 * 2;
    unsigned short* Wt0 = (unsigned short*)p; p += 128 * 64 * 2;
    unsigned short* Wt1 = (unsigned short*)p; p += 256 * 64 * 2;
    unsigned short* Wt2 = (unsigned short*)p; p += 256 * 64 * 2;
    int* off = (int*)p;             p += (((size_t)N + 1 + 63) / 64) * 64 * 4;
    int* cnt = (int*)p;             p += (((size_t)N + 63) / 64) * 64 * 4;
    int* cursor = (int*)p;          p += (((size_t)N + 63) / 64) * 64 * 4;
    int* ssorted = (int*)p;         p += (size_t)E * 4;                 // 1.6 MB

    hipMemsetAsync(flag, 0, 4, stream);
    detect_kernel<<<16, 256, 0, stream>>>((const unsigned short*)nodes, flag);

    // dtype-dependent preps
    long nelem = (long)N * 128;
    prep_a<<<(int)((nelem + 1023) / 1024), 256, 0, stream>>>(nodes, flag, nh, nl, nelem);
    prep_w<<<(128 * 64 + 255) / 256, 256, 0, stream>>>(Wq0, flag, Wt0, 128);
    prep_w<<<(256 * 64 + 255) / 256, 256, 0, stream>>>(Wq1, flag, Wt1, 256);
    prep_w<<<(256 * 64 + 255) / 256, 256, 0, stream>>>(Wq2, flag, Wt2, 256);

    // CSR build (edges fixed for all 3 layers)
    hipMemsetAsync(cnt, 0, (size_t)N * sizeof(int), stream);
    hist_kernel<<<(E + 255) / 256, 256, 0, stream>>>(receivers, cnt, E);
    scan_kernel<<<1, 1024, 0, stream>>>(cnt, off, cursor, N);
    scatter_kernel<<<(E + 255) / 256, 256, 0, stream>>>(receivers, senders, cursor, ssorted, E);

    int attnGrid = (N + 3) / 4;
    int tiles = (N + 15) / 16;
    int gemmGrid = (tiles + 3) / 4;

    // layer 0
    gemm_mfma<128><<<gemmGrid, 256, 0, stream>>>(nh, nl, Wt0, bq0, flag, h, N, 0);
    attn_kernel<<<attnGrid, 256, 0, stream>>>(h, off, ssorted, Wl0, bl0, flag,
                                              xh, xl, nullptr, N, 0);
    // layer 1
    gemm_mfma<256><<<gemmGrid, 256, 0, stream>>>(xh, xl, Wt1, bq1, flag, h, N, 1);
    attn_kernel<<<attnGrid, 256, 0, stream>>>(h, off, ssorted, Wl1, bl1, flag,
                                              xh, xl, nullptr, N, 0);
    // layer 2 (last: mean over heads + elu)
    gemm_mfma<256><<<gemmGrid, 256, 0, stream>>>(xh, xl, Wt2, bq2, flag, h, N, 1);
    attn_kernel<<<attnGrid, 256, 0, stream>>>(h, off, ssorted, Wl2, bl2, flag,
                                              nullptr, nullptr, d_out, N, 1);
}

// Round 6
// 312.173 us; speedup vs baseline: 1.1473x; 1.1473x over previous
//
#include <hip/hip_runtime.h>
#include <hip/hip_bf16.h>

#define HID 64
#define HEADS 4

typedef short s16x8 __attribute__((ext_vector_type(8)));   // 8 bf16 (4 VGPRs)
typedef short s16x4 __attribute__((ext_vector_type(4)));
typedef float f32x4 __attribute__((ext_vector_type(4)));
typedef float f32x2 __attribute__((ext_vector_type(2)));   // candidates for v_pk_*_f32

// flag convention: *flag >= 8  =>  float inputs are fp32; else bf16.
__device__ __forceinline__ float ldw(const void* p, long i, bool f32) {
    return f32 ? ((const float*)p)[i] : (float)((const __hip_bfloat16*)p)[i];
}

__device__ __forceinline__ unsigned short f2b(float f) {   // fp32 -> bf16 bits (RNE, finite)
    unsigned int u = __builtin_bit_cast(unsigned int, f);
    u += 0x7FFF + ((u >> 16) & 1);
    return (unsigned short)(u >> 16);
}
__device__ __forceinline__ float b2f(unsigned short s) {
    unsigned int u = ((unsigned int)s) << 16;
    return __builtin_bit_cast(float, u);
}

#if __has_builtin(__builtin_amdgcn_exp2f)
#define EXP2(x) __builtin_amdgcn_exp2f(x)     // guaranteed single v_exp_f32
#else
#define EXP2(x) exp2f(x)
#endif
#if __has_builtin(__builtin_amdgcn_rcpf)
#define RCP(x) __builtin_amdgcn_rcpf(x)
#else
#define RCP(x) (1.0f / (x))
#endif

// ---------------- dtype probe (16 blocks, coalesced) ----------------
__global__ void detect_kernel(const unsigned short* __restrict__ p, int* __restrict__ flag) {
    int gtid = blockIdx.x * 256 + threadIdx.x;   // 4096 threads x 8 words = 32768
    int hits = 0;
    #pragma unroll
    for (int k = 0; k < 8; k++) {
        unsigned short v = p[gtid + k * 4096];
        if (((v >> 7) & 0xFF) == 0xFF) hits++;   // bf16 NaN/Inf exponent pattern
    }
    if (hits) atomicAdd(flag, hits);
}

// ---------------- prep: A (activations/nodes) -> bf16 hi/lo planes ----------------
__global__ void prep_a(const void* __restrict__ src, const int* __restrict__ flag,
                       unsigned short* __restrict__ hi, unsigned short* __restrict__ lo,
                       long n) {
    const bool f32 = (*flag >= 8);
    long i = (long)blockIdx.x * 1024 + (long)threadIdx.x * 4;
    if (i >= n) return;
    s16x4 vh, vl;
    if (f32) {
        f32x4 v = *(const f32x4*)((const float*)src + i);
        #pragma unroll
        for (int j = 0; j < 4; j++) {
            unsigned short hb = f2b(v[j]);
            vh[j] = (short)hb;
            vl[j] = (short)f2b(v[j] - b2f(hb));
        }
    } else {
        vh = *(const s16x4*)((const unsigned short*)src + i);
        vl = (s16x4){0, 0, 0, 0};
    }
    *(s16x4*)(hi + i) = vh;
    *(s16x4*)(lo + i) = vl;
}

// ---------------- prep: W [K,64] -> W^T bf16 [64,K] ----------------
__global__ void prep_w(const void* __restrict__ W, const int* __restrict__ flag,
                       unsigned short* __restrict__ Wt, int K) {
    const bool f32 = (*flag >= 8);
    int i = blockIdx.x * 256 + threadIdx.x;
    if (i < K * 64) {
        int k = i >> 6, n = i & 63;
        Wt[n * K + k] = f2b(ldw(W, i, f32));
    }
}

// ---------------- CSR build ----------------

__global__ void hist_kernel(const int* __restrict__ recv, int* __restrict__ cnt, int E) {
    int i = blockIdx.x * blockDim.x + threadIdx.x;
    if (i < E) atomicAdd(&cnt[recv[i]], 1);
}

__global__ __launch_bounds__(1024) void scan_kernel(const int* __restrict__ cnt,
                                                    int* __restrict__ off,
                                                    int* __restrict__ cursor, int n) {
    const int C = (n + 1023) >> 10;          // assume <= 32
    int tid = threadIdx.x;
    int base = tid * C;
    int v[32];
    int tot = 0;
    for (int j = 0; j < C; j++) {
        int idx = base + j;
        int x = (idx < n) ? cnt[idx] : 0;
        v[j] = tot;
        tot += x;
    }
    int lane = tid & 63, w = tid >> 6;
    int incl = tot;
    #pragma unroll
    for (int s = 1; s < 64; s <<= 1) {
        int t = __shfl_up(incl, s, 64);
        if (lane >= s) incl += t;
    }
    __shared__ int wsum[16];
    __shared__ int woff[16];
    if (lane == 63) wsum[w] = incl;
    __syncthreads();
    if (tid < 16) {
        int s = 0;
        for (int i = 0; i < tid; i++) s += wsum[i];
        woff[tid] = s;
    }
    __syncthreads();
    int toff = woff[w] + (incl - tot);
    for (int j = 0; j < C; j++) {
        int idx = base + j;
        if (idx < n) { off[idx] = toff + v[j]; cursor[idx] = toff + v[j]; }
    }
    if (tid == 1023) off[n] = toff + tot;
}

__global__ void scatter_kernel(const int* __restrict__ recv, const int* __restrict__ send,
                               int* __restrict__ cursor, int* __restrict__ ssorted, int E) {
    int i = blockIdx.x * blockDim.x + threadIdx.x;
    if (i < E) {
        int pos = atomicAdd(&cursor[recv[i]], 1);
        ssorted[pos] = send[i];
    }
}

// ---------------- MFMA GEMM: h = A @ W + b,  A = Ah + Al (bf16 planes) ----------------

template <int K>
__global__ __launch_bounds__(256) void gemm_mfma(const unsigned short* __restrict__ Ah,
                                                 const unsigned short* __restrict__ Al,
                                                 const unsigned short* __restrict__ Wt,
                                                 const void* __restrict__ bq,
                                                 const int* __restrict__ flag,
                                                 float* __restrict__ h, int M, int lo_always) {
    const bool f32 = (*flag >= 8);
    const bool use_lo = lo_always || f32;
    int lane = threadIdx.x & 63, wv = threadIdx.x >> 6;
    int m16 = lane & 15, quad = lane >> 4;

    int tiles = (M + 15) >> 4;
    int tile = blockIdx.x * 4 + wv;
    if (tile >= tiles) return;

    float bias[4];
    #pragma unroll
    for (int t = 0; t < 4; t++) bias[t] = ldw(bq, 16 * t + m16, f32);

    int m0 = tile << 4;
    int row = m0 + m16;
    bool rv = row < M;
    long abase = (long)row * K;
    f32x4 acc[4] = {{0.f,0.f,0.f,0.f},{0.f,0.f,0.f,0.f},{0.f,0.f,0.f,0.f},{0.f,0.f,0.f,0.f}};

    #pragma unroll
    for (int ks = 0; ks < K / 32; ks++) {
        int kb = ks * 32 + quad * 8;
        s16x8 b[4];
        #pragma unroll
        for (int t = 0; t < 4; t++)
            b[t] = *(const s16x8*)(Wt + (16 * t + m16) * K + kb);
        s16x8 ah = rv ? *(const s16x8*)(Ah + abase + kb) : (s16x8){0,0,0,0,0,0,0,0};
        #pragma unroll
        for (int t = 0; t < 4; t++)
            acc[t] = __builtin_amdgcn_mfma_f32_16x16x32_bf16(ah, b[t], acc[t], 0, 0, 0);
        if (use_lo) {
            s16x8 al = rv ? *(const s16x8*)(Al + abase + kb) : (s16x8){0,0,0,0,0,0,0,0};
            #pragma unroll
            for (int t = 0; t < 4; t++)
                acc[t] = __builtin_amdgcn_mfma_f32_16x16x32_bf16(al, b[t], acc[t], 0, 0, 0);
        }
    }

    #pragma unroll
    for (int t = 0; t < 4; t++) {
        #pragma unroll
        for (int r = 0; r < 4; r++) {
            int orow = m0 + quad * 4 + r;        // C/D: col=lane&15, row=quad*4+reg
            if (orow < M) h[(long)orow * 64 + 16 * t + m16] = acc[t][r] + bias[t];
        }
    }
}

// ---------------- Attention: segment softmax (no-max, exp2-folded) + aggregate ----
// One wave per receiver; lane = hidden dim. Sender ids for the whole segment are
// bulk-loaded 64-at-a-time into a lane register and extracted with v_readlane
// (no per-iteration s_load chain). Edge loop unrolled x2 with 2 gathers in flight.
// Heads packed in f32x2 pairs (v_pk_*_f32 capable). exp via raw v_exp_f32.
// Numerics: logits O(1) (verified R3-R5: absmax = 1 bf16 ulp) -> no-max softmax
// safe; log2(e) folded into weights (leaky(z)*c == leaky(z*c), c>0).

__global__ __launch_bounds__(256) void attn_kernel(
    const float* __restrict__ h, const int* __restrict__ off,
    const int* __restrict__ ssorted,
    const void* __restrict__ Wl, const void* __restrict__ bl,
    const int* __restrict__ flag,
    unsigned short* __restrict__ xh, unsigned short* __restrict__ xl,
    void* __restrict__ out, int n, int last) {
    const bool f32 = (*flag >= 8);
    int lane = threadIdx.x & 63;
    int r = __builtin_amdgcn_readfirstlane(blockIdx.x * 4 + (threadIdx.x >> 6));
    if (r >= n) return;

    const float LOG2E = 1.44269504f;
    float hr = h[(long)r * HID + lane];
    f32x2 w0p[2], cp[2];
    #pragma unroll
    for (int q = 0; q < 2; q++) {
        #pragma unroll
        for (int c = 0; c < 2; c++) {
            int k = 2 * q + c;
            float w0 = ldw(Wl, k, f32) * LOG2E;
            float w1 = ldw(Wl, HEADS + k, f32) * LOG2E;
            float bb = ldw(bl, k, f32) * LOG2E;
            w0p[q][c] = w0;
            cp[q][c] = fmaf(hr, w1, bb);     // receiver part: loop-invariant
        }
    }

    f32x2 lp[2] = {{0.f, 0.f}, {0.f, 0.f}};
    f32x2 ap[2] = {{0.f, 0.f}, {0.f, 0.f}};
    const float* hb = h + lane;              // gather base for this lane's dim

    int start = off[r], end = off[r + 1];    // scalar (r wave-uniform)

    for (int base = start; base < end; base += 64) {
        int idx = base + lane;
        int sv = ssorted[(idx < end) ? idx : (end - 1)];   // one vector load / 64 edges
        int cnt = min(64, end - base);

        #define LD(j) hb[(long)__builtin_amdgcn_readlane(sv, (j)) * HID]
        #define STEP(hc) {                                                     \
            float _h = (hc);                                                   \
            _Pragma("unroll")                                                  \
            for (int q = 0; q < 2; q++) {                                      \
                f32x2 t = w0p[q] * _h + cp[q];                                 \
                f32x2 u = t * 0.2f;                                            \
                t.x = fmaxf(t.x, u.x); t.y = fmaxf(t.y, u.y);                  \
                f32x2 pe; pe.x = EXP2(t.x); pe.y = EXP2(t.y);                  \
                lp[q] += pe;                                                   \
                ap[q] += pe * _h;                                              \
            } }

        float h0 = LD(0);
        float h1 = (cnt > 1) ? LD(1) : 0.f;
        int j = 0;
        for (; j + 2 <= cnt; j += 2) {
            float a0 = h0, a1 = h1;
            int rem = cnt - j - 2;
            if (rem > 0) h0 = LD(j + 2);     // keep 2 gathers in flight
            if (rem > 1) h1 = LD(j + 3);
            STEP(a0);
            STEP(a1);
        }
        if (j < cnt) STEP(h0);               // lone tail edge
        #undef LD
        #undef STEP
    }

    bool has = (end > start);
    if (!last) {
        float v[4];
        #pragma unroll
        for (int k = 0; k < HEADS; k++) {
            float a = has ? ap[k >> 1][k & 1] * RCP(lp[k >> 1][k & 1]) : 0.f;
            v[k] = (a > 0.f) ? a : (__expf(a) - 1.f);    // elu
        }
        s16x4 vh, vlo;
        #pragma unroll
        for (int k = 0; k < HEADS; k++) {                // split for next GEMM's A planes
            unsigned short hbk = f2b(v[k]);
            vh[k] = (short)hbk;
            vlo[k] = (short)f2b(v[k] - b2f(hbk));
        }
        long o = (long)r * (HID * HEADS) + lane * HEADS; // reshape: d*HEADS+k
        *(s16x4*)(xh + o) = vh;
        *(s16x4*)(xl + o) = vlo;
    } else {
        float s = 0.f;
        #pragma unroll
        for (int k = 0; k < HEADS; k++)
            s += has ? ap[k >> 1][k & 1] * RCP(lp[k >> 1][k & 1]) : 0.f;
        float a = s * 0.25f;                             // mean over heads
        a = (a > 0.f) ? a : (__expf(a) - 1.f);           // elu
        if (f32) ((float*)out)[(long)r * HID + lane] = a;
        else     ((__hip_bfloat16*)out)[(long)r * HID + lane] = (__hip_bfloat16)a;
    }
}

// ---------------- launch ----------------

extern "C" void kernel_launch(void* const* d_in, const int* in_sizes, int n_in,
                              void* d_out, int out_size, void* d_ws, size_t ws_size,
                              hipStream_t stream) {
    const void* nodes    = d_in[0];
    const int* senders   = (const int*)d_in[1];
    const int* receivers = (const int*)d_in[2];
    const void* Wq0 = d_in[3];  const void* bq0 = d_in[4];
    const void* Wl0 = d_in[5];  const void* bl0 = d_in[6];
    const void* Wq1 = d_in[7];  const void* bq1 = d_in[8];
    const void* Wl1 = d_in[9];  const void* bl1 = d_in[10];
    const void* Wq2 = d_in[11]; const void* bq2 = d_in[12];
    const void* Wl2 = d_in[13]; const void* bl2 = d_in[14];

    int N = in_sizes[0] / 128;
    int E = in_sizes[1];

    char* p = (char*)d_ws;
    int* flag = (int*)p;            p += 64;
    float* h = (float*)p;           p += (size_t)N * 64 * 4;            // 6.4 MB
    unsigned short* nh = (unsigned short*)p;  p += (size_t)N * 128 * 2; // 6.4 MB
    unsigned short* nl = (unsigned short*)p;  p += (size_t)N * 128 * 2;
    unsigned short* xh = (unsigned short*)p;  p += (size_t)N * 256 * 2; // 12.8 MB
    unsigned short* xl = (unsigned short*)p;  p += (size_t)N * 256 * 2;
    unsigned short* Wt0 = (unsigned short*)p; p += 128 * 64 * 2;
    unsigned short* Wt1 = (unsigned short*)p; p += 256 * 64 * 2;
    unsigned short* Wt2 = (unsigned short*)p; p += 256 * 64 * 2;
    int* off = (int*)p;             p += (((size_t)N + 1 + 63) / 64) * 64 * 4;
    int* cnt = (int*)p;             p += (((size_t)N + 63) / 64) * 64 * 4;
    int* cursor = (int*)p;          p += (((size_t)N + 63) / 64) * 64 * 4;
    int* ssorted = (int*)p;         p += (size_t)E * 4;                 // 1.6 MB

    hipMemsetAsync(flag, 0, 4, stream);
    detect_kernel<<<16, 256, 0, stream>>>((const unsigned short*)nodes, flag);

    // dtype-dependent preps
    long nelem = (long)N * 128;
    prep_a<<<(int)((nelem + 1023) / 1024), 256, 0, stream>>>(nodes, flag, nh, nl, nelem);
    prep_w<<<(128 * 64 + 255) / 256, 256, 0, stream>>>(Wq0, flag, Wt0, 128);
    prep_w<<<(256 * 64 + 255) / 256, 256, 0, stream>>>(Wq1, flag, Wt1, 256);
    prep_w<<<(256 * 64 + 255) / 256, 256, 0, stream>>>(Wq2, flag, Wt2, 256);

    // CSR build (edges fixed for all 3 layers)
    hipMemsetAsync(cnt, 0, (size_t)N * sizeof(int), stream);
    hist_kernel<<<(E + 255) / 256, 256, 0, stream>>>(receivers, cnt, E);
    scan_kernel<<<1, 1024, 0, stream>>>(cnt, off, cursor, N);
    scatter_kernel<<<(E + 255) / 256, 256, 0, stream>>>(receivers, senders, cursor, ssorted, E);

    int attnGrid = (N + 3) / 4;
    int tiles = (N + 15) / 16;
    int gemmGrid = (tiles + 3) / 4;

    // layer 0
    gemm_mfma<128><<<gemmGrid, 256, 0, stream>>>(nh, nl, Wt0, bq0, flag, h, N, 0);
    attn_kernel<<<attnGrid, 256, 0, stream>>>(h, off, ssorted, Wl0, bl0, flag,
                                              xh, xl, nullptr, N, 0);
    // layer 1
    gemm_mfma<256><<<gemmGrid, 256, 0, stream>>>(xh, xl, Wt1, bq1, flag, h, N, 1);
    attn_kernel<<<attnGrid, 256, 0, stream>>>(h, off, ssorted, Wl1, bl1, flag,
                                              xh, xl, nullptr, N, 0);
    // layer 2 (last: mean over heads + elu)
    gemm_mfma<256><<<gemmGrid, 256, 0, stream>>>(xh, xl, Wt2, bq2, flag, h, N, 1);
    attn_kernel<<<attnGrid, 256, 0, stream>>>(h, off, ssorted, Wl2, bl2, flag,
                                              nullptr, nullptr, d_out, N, 1);
}

// Round 7
// 305.158 us; speedup vs baseline: 1.1737x; 1.0230x over previous
//
#include <hip/hip_runtime.h>
#include <hip/hip_bf16.h>

#define HID 64
#define HEADS 4

typedef short s16x8 __attribute__((ext_vector_type(8)));   // 8 bf16 (4 VGPRs)
typedef short s16x4 __attribute__((ext_vector_type(4)));
typedef float f32x4 __attribute__((ext_vector_type(4)));
typedef float f32x2 __attribute__((ext_vector_type(2)));   // candidates for v_pk_*_f32

// flag convention: *flag >= 8  =>  float inputs are fp32; else bf16.
__device__ __forceinline__ float ldw(const void* p, long i, bool f32) {
    return f32 ? ((const float*)p)[i] : (float)((const __hip_bfloat16*)p)[i];
}

__device__ __forceinline__ unsigned short f2b(float f) {   // fp32 -> bf16 bits (RNE, finite)
    unsigned int u = __builtin_bit_cast(unsigned int, f);
    u += 0x7FFF + ((u >> 16) & 1);
    return (unsigned short)(u >> 16);
}
__device__ __forceinline__ float b2f(unsigned short s) {
    unsigned int u = ((unsigned int)s) << 16;
    return __builtin_bit_cast(float, u);
}

#if __has_builtin(__builtin_amdgcn_exp2f)
#define EXP2(x) __builtin_amdgcn_exp2f(x)     // guaranteed single v_exp_f32
#else
#define EXP2(x) exp2f(x)
#endif
#if __has_builtin(__builtin_amdgcn_rcpf)
#define RCP(x) __builtin_amdgcn_rcpf(x)
#else
#define RCP(x) (1.0f / (x))
#endif

// ---------------- dtype probe (16 blocks, coalesced) ----------------
__global__ void detect_kernel(const unsigned short* __restrict__ p, int* __restrict__ flag) {
    int gtid = blockIdx.x * 256 + threadIdx.x;   // 4096 threads x 8 words = 32768
    int hits = 0;
    #pragma unroll
    for (int k = 0; k < 8; k++) {
        unsigned short v = p[gtid + k * 4096];
        if (((v >> 7) & 0xFF) == 0xFF) hits++;   // bf16 NaN/Inf exponent pattern
    }
    if (hits) atomicAdd(flag, hits);
}

// ---------------- prep: A (activations/nodes) -> bf16 hi/lo planes ----------------
__global__ void prep_a(const void* __restrict__ src, const int* __restrict__ flag,
                       unsigned short* __restrict__ hi, unsigned short* __restrict__ lo,
                       long n) {
    const bool f32 = (*flag >= 8);
    long i = (long)blockIdx.x * 1024 + (long)threadIdx.x * 4;
    if (i >= n) return;
    s16x4 vh, vl;
    if (f32) {
        f32x4 v = *(const f32x4*)((const float*)src + i);
        #pragma unroll
        for (int j = 0; j < 4; j++) {
            unsigned short hb = f2b(v[j]);
            vh[j] = (short)hb;
            vl[j] = (short)f2b(v[j] - b2f(hb));
        }
    } else {
        vh = *(const s16x4*)((const unsigned short*)src + i);
        vl = (s16x4){0, 0, 0, 0};
    }
    *(s16x4*)(hi + i) = vh;
    *(s16x4*)(lo + i) = vl;
}

// ---------------- prep: all three W [K,64] -> W^T bf16 [64,K], one launch ----------
__global__ void prep_w_all(const void* __restrict__ W0, const void* __restrict__ W1,
                           const void* __restrict__ W2, const int* __restrict__ flag,
                           unsigned short* __restrict__ T0, unsigned short* __restrict__ T1,
                           unsigned short* __restrict__ T2) {
    const bool f32 = (*flag >= 8);
    int i = blockIdx.x * 256 + threadIdx.x;
    const void* W; unsigned short* T; int K, o;
    if (i < 8192)       { W = W0; T = T0; K = 128; o = i; }
    else if (i < 24576) { W = W1; T = T1; K = 256; o = i - 8192; }
    else if (i < 40960) { W = W2; T = T2; K = 256; o = i - 24576; }
    else return;
    int k = o >> 6, n = o & 63;
    T[n * K + k] = f2b(ldw(W, o, f32));
}

// ---------------- CSR build ----------------

__global__ void hist_kernel(const int* __restrict__ recv, int* __restrict__ cnt, int E) {
    int i = blockIdx.x * blockDim.x + threadIdx.x;
    if (i < E) atomicAdd(&cnt[recv[i]], 1);
}

__global__ __launch_bounds__(1024) void scan_kernel(const int* __restrict__ cnt,
                                                    int* __restrict__ off,
                                                    int* __restrict__ cursor, int n) {
    const int C = (n + 1023) >> 10;          // assume <= 32
    int tid = threadIdx.x;
    int base = tid * C;
    int v[32];
    int tot = 0;
    for (int j = 0; j < C; j++) {
        int idx = base + j;
        int x = (idx < n) ? cnt[idx] : 0;
        v[j] = tot;
        tot += x;
    }
    int lane = tid & 63, w = tid >> 6;
    int incl = tot;
    #pragma unroll
    for (int s = 1; s < 64; s <<= 1) {
        int t = __shfl_up(incl, s, 64);
        if (lane >= s) incl += t;
    }
    __shared__ int wsum[16];
    __shared__ int woff[16];
    if (lane == 63) wsum[w] = incl;
    __syncthreads();
    if (tid < 16) {
        int s = 0;
        for (int i = 0; i < tid; i++) s += wsum[i];
        woff[tid] = s;
    }
    __syncthreads();
    int toff = woff[w] + (incl - tot);
    for (int j = 0; j < C; j++) {
        int idx = base + j;
        if (idx < n) { off[idx] = toff + v[j]; cursor[idx] = toff + v[j]; }
    }
    if (tid == 1023) off[n] = toff + tot;
}

__global__ void scatter_kernel(const int* __restrict__ recv, const int* __restrict__ send,
                               int* __restrict__ cursor, int* __restrict__ ssorted, int E) {
    int i = blockIdx.x * blockDim.x + threadIdx.x;
    if (i < E) {
        int pos = atomicAdd(&cursor[recv[i]], 1);
        ssorted[pos] = send[i];
    }
}

// ---------------- MFMA GEMM: h = A @ W + b,  A = Ah + Al (bf16 planes) ----------------

template <int K>
__global__ __launch_bounds__(256) void gemm_mfma(const unsigned short* __restrict__ Ah,
                                                 const unsigned short* __restrict__ Al,
                                                 const unsigned short* __restrict__ Wt,
                                                 const void* __restrict__ bq,
                                                 const int* __restrict__ flag,
                                                 float* __restrict__ h, int M, int lo_always) {
    const bool f32 = (*flag >= 8);
    const bool use_lo = lo_always || f32;
    int lane = threadIdx.x & 63, wv = threadIdx.x >> 6;
    int m16 = lane & 15, quad = lane >> 4;

    int tiles = (M + 15) >> 4;
    int tile = blockIdx.x * 4 + wv;
    if (tile >= tiles) return;

    float bias[4];
    #pragma unroll
    for (int t = 0; t < 4; t++) bias[t] = ldw(bq, 16 * t + m16, f32);

    int m0 = tile << 4;
    int row = m0 + m16;
    bool rv = row < M;
    long abase = (long)row * K;
    f32x4 acc[4] = {{0.f,0.f,0.f,0.f},{0.f,0.f,0.f,0.f},{0.f,0.f,0.f,0.f},{0.f,0.f,0.f,0.f}};

    #pragma unroll
    for (int ks = 0; ks < K / 32; ks++) {
        int kb = ks * 32 + quad * 8;
        s16x8 b[4];
        #pragma unroll
        for (int t = 0; t < 4; t++)
            b[t] = *(const s16x8*)(Wt + (16 * t + m16) * K + kb);
        s16x8 ah = rv ? *(const s16x8*)(Ah + abase + kb) : (s16x8){0,0,0,0,0,0,0,0};
        #pragma unroll
        for (int t = 0; t < 4; t++)
            acc[t] = __builtin_amdgcn_mfma_f32_16x16x32_bf16(ah, b[t], acc[t], 0, 0, 0);
        if (use_lo) {
            s16x8 al = rv ? *(const s16x8*)(Al + abase + kb) : (s16x8){0,0,0,0,0,0,0,0};
            #pragma unroll
            for (int t = 0; t < 4; t++)
                acc[t] = __builtin_amdgcn_mfma_f32_16x16x32_bf16(al, b[t], acc[t], 0, 0, 0);
        }
    }

    #pragma unroll
    for (int t = 0; t < 4; t++) {
        #pragma unroll
        for (int r = 0; r < 4; r++) {
            int orow = m0 + quad * 4 + r;        // C/D: col=lane&15, row=quad*4+reg
            if (orow < M) h[(long)orow * 64 + 16 * t + m16] = acc[t][r] + bias[t];
        }
    }
}

// ---------------- Attention: segment softmax (no-max, exp2-folded) + aggregate ----
// One wave per receiver; lane = hidden dim. Sender ids bulk-loaded 64/chunk into a
// lane register, extracted with v_readlane (no s_load chain). Gather pipeline is
// DEPTH-4: four h-rows in flight to cover ~200-400cy L2/L3 latency (R6 post-mortem:
// depth-2 left ~2x latency exposure). All control flow is wave-uniform; hq[] only
// indexed with compile-time constants (no scratch).
// Numerics: logits O(1) (verified R3-R6: absmax = 1 bf16 ulp) -> no-max softmax
// safe; log2(e) folded into weights (leaky(z)*c == leaky(z*c), c>0) -> raw exp2.

__global__ __launch_bounds__(256) void attn_kernel(
    const float* __restrict__ h, const int* __restrict__ off,
    const int* __restrict__ ssorted,
    const void* __restrict__ Wl, const void* __restrict__ bl,
    const int* __restrict__ flag,
    unsigned short* __restrict__ xh, unsigned short* __restrict__ xl,
    void* __restrict__ out, int n, int last) {
    const bool f32 = (*flag >= 8);
    int lane = threadIdx.x & 63;
    int r = __builtin_amdgcn_readfirstlane(blockIdx.x * 4 + (threadIdx.x >> 6));
    if (r >= n) return;

    const float LOG2E = 1.44269504f;
    float hr = h[(long)r * HID + lane];
    f32x2 w0p[2], cp[2];
    #pragma unroll
    for (int q = 0; q < 2; q++) {
        #pragma unroll
        for (int c = 0; c < 2; c++) {
            int k = 2 * q + c;
            float w0 = ldw(Wl, k, f32) * LOG2E;
            float w1 = ldw(Wl, HEADS + k, f32) * LOG2E;
            float bb = ldw(bl, k, f32) * LOG2E;
            w0p[q][c] = w0;
            cp[q][c] = fmaf(hr, w1, bb);     // receiver part: loop-invariant
        }
    }

    f32x2 lp[2] = {{0.f, 0.f}, {0.f, 0.f}};
    f32x2 ap[2] = {{0.f, 0.f}, {0.f, 0.f}};
    const float* hbp = h + lane;             // gather base for this lane's dim

    int start = off[r], end = off[r + 1];    // scalar (r wave-uniform)

    for (int base = start; base < end; base += 64) {
        int idx = base + lane;
        int sv = ssorted[(idx < end) ? idx : (end - 1)];   // one vector load / 64 edges
        int cnt = min(64, end - base);

        #define LD(j) hbp[(long)__builtin_amdgcn_readlane(sv, (j)) * HID]
        #define STEP(hc) {                                                     \
            float _h = (hc);                                                   \
            _Pragma("unroll")                                                  \
            for (int q = 0; q < 2; q++) {                                      \
                f32x2 t = w0p[q] * _h + cp[q];                                 \
                f32x2 u = t * 0.2f;                                            \
                t.x = fmaxf(t.x, u.x); t.y = fmaxf(t.y, u.y);                  \
                f32x2 pe; pe.x = EXP2(t.x); pe.y = EXP2(t.y);                  \
                lp[q] += pe;                                                   \
                ap[q] += pe * _h;                                              \
            } }

        float hq0 = (0 < cnt) ? LD(0) : 0.f;     // depth-4 pipeline prologue
        float hq1 = (1 < cnt) ? LD(1) : 0.f;
        float hq2 = (2 < cnt) ? LD(2) : 0.f;
        float hq3 = (3 < cnt) ? LD(3) : 0.f;
        int j = 0;
        for (; j + 4 <= cnt; j += 4) {
            float a0 = hq0, a1 = hq1, a2 = hq2, a3 = hq3;
            if (j + 4 < cnt) hq0 = LD(j + 4);    // refill: 4 gathers in flight
            if (j + 5 < cnt) hq1 = LD(j + 5);
            if (j + 6 < cnt) hq2 = LD(j + 6);
            if (j + 7 < cnt) hq3 = LD(j + 7);
            STEP(a0); STEP(a1); STEP(a2); STEP(a3);
        }
        int remn = cnt - j;                      // 0..3 tail, registers already loaded
        if (remn > 0) STEP(hq0);
        if (remn > 1) STEP(hq1);
        if (remn > 2) STEP(hq2);
        #undef LD
        #undef STEP
    }

    bool has = (end > start);
    if (!last) {
        float v[4];
        #pragma unroll
        for (int k = 0; k < HEADS; k++) {
            float a = has ? ap[k >> 1][k & 1] * RCP(lp[k >> 1][k & 1]) : 0.f;
            v[k] = (a > 0.f) ? a : (__expf(a) - 1.f);    // elu
        }
        s16x4 vh, vlo;
        #pragma unroll
        for (int k = 0; k < HEADS; k++) {                // split for next GEMM's A planes
            unsigned short hbk = f2b(v[k]);
            vh[k] = (short)hbk;
            vlo[k] = (short)f2b(v[k] - b2f(hbk));
        }
        long o = (long)r * (HID * HEADS) + lane * HEADS; // reshape: d*HEADS+k
        *(s16x4*)(xh + o) = vh;
        *(s16x4*)(xl + o) = vlo;
    } else {
        float s = 0.f;
        #pragma unroll
        for (int k = 0; k < HEADS; k++)
            s += has ? ap[k >> 1][k & 1] * RCP(lp[k >> 1][k & 1]) : 0.f;
        float a = s * 0.25f;                             // mean over heads
        a = (a > 0.f) ? a : (__expf(a) - 1.f);           // elu
        if (f32) ((float*)out)[(long)r * HID + lane] = a;
        else     ((__hip_bfloat16*)out)[(long)r * HID + lane] = (__hip_bfloat16)a;
    }
}

// ---------------- launch ----------------

extern "C" void kernel_launch(void* const* d_in, const int* in_sizes, int n_in,
                              void* d_out, int out_size, void* d_ws, size_t ws_size,
                              hipStream_t stream) {
    const void* nodes    = d_in[0];
    const int* senders   = (const int*)d_in[1];
    const int* receivers = (const int*)d_in[2];
    const void* Wq0 = d_in[3];  const void* bq0 = d_in[4];
    const void* Wl0 = d_in[5];  const void* bl0 = d_in[6];
    const void* Wq1 = d_in[7];  const void* bq1 = d_in[8];
    const void* Wl1 = d_in[9];  const void* bl1 = d_in[10];
    const void* Wq2 = d_in[11]; const void* bq2 = d_in[12];
    const void* Wl2 = d_in[13]; const void* bl2 = d_in[14];

    int N = in_sizes[0] / 128;
    int E = in_sizes[1];

    char* p = (char*)d_ws;
    int* flag = (int*)p;            p += 64;
    float* h = (float*)p;           p += (size_t)N * 64 * 4;            // 6.4 MB
    unsigned short* nh = (unsigned short*)p;  p += (size_t)N * 128 * 2; // 6.4 MB
    unsigned short* nl = (unsigned short*)p;  p += (size_t)N * 128 * 2;
    unsigned short* xh = (unsigned short*)p;  p += (size_t)N * 256 * 2; // 12.8 MB
    unsigned short* xl = (unsigned short*)p;  p += (size_t)N * 256 * 2;
    unsigned short* Wt0 = (unsigned short*)p; p += 128 * 64 * 2;
    unsigned short* Wt1 = (unsigned short*)p; p += 256 * 64 * 2;
    unsigned short* Wt2 = (unsigned short*)p; p += 256 * 64 * 2;
    int* off = (int*)p;             p += (((size_t)N + 1 + 63) / 64) * 64 * 4;
    int* cnt = (int*)p;             p += (((size_t)N + 63) / 64) * 64 * 4;
    int* cursor = (int*)p;          p += (((size_t)N + 63) / 64) * 64 * 4;
    int* ssorted = (int*)p;         p += (size_t)E * 4;                 // 1.6 MB

    hipMemsetAsync(flag, 0, 4, stream);
    detect_kernel<<<16, 256, 0, stream>>>((const unsigned short*)nodes, flag);

    // dtype-dependent preps
    long nelem = (long)N * 128;
    prep_a<<<(int)((nelem + 1023) / 1024), 256, 0, stream>>>(nodes, flag, nh, nl, nelem);
    prep_w_all<<<160, 256, 0, stream>>>(Wq0, Wq1, Wq2, flag, Wt0, Wt1, Wt2);

    // CSR build (edges fixed for all 3 layers)
    hipMemsetAsync(cnt, 0, (size_t)N * sizeof(int), stream);
    hist_kernel<<<(E + 255) / 256, 256, 0, stream>>>(receivers, cnt, E);
    scan_kernel<<<1, 1024, 0, stream>>>(cnt, off, cursor, N);
    scatter_kernel<<<(E + 255) / 256, 256, 0, stream>>>(receivers, senders, cursor, ssorted, E);

    int attnGrid = (N + 3) / 4;
    int tiles = (N + 15) / 16;
    int gemmGrid = (tiles + 3) / 4;

    // layer 0
    gemm_mfma<128><<<gemmGrid, 256, 0, stream>>>(nh, nl, Wt0, bq0, flag, h, N, 0);
    attn_kernel<<<attnGrid, 256, 0, stream>>>(h, off, ssorted, Wl0, bl0, flag,
                                              xh, xl, nullptr, N, 0);
    // layer 1
    gemm_mfma<256><<<gemmGrid, 256, 0, stream>>>(xh, xl, Wt1, bq1, flag, h, N, 1);
    attn_kernel<<<attnGrid, 256, 0, stream>>>(h, off, ssorted, Wl1, bl1, flag,
                                              xh, xl, nullptr, N, 0);
    // layer 2 (last: mean over heads + elu)
    gemm_mfma<256><<<gemmGrid, 256, 0, stream>>>(xh, xl, Wt2, bq2, flag, h, N, 1);
    attn_kernel<<<attnGrid, 256, 0, stream>>>(h, off, ssorted, Wl2, bl2, flag,
                                              nullptr, nullptr, d_out, N, 1);
}

// Round 8
// 289.451 us; speedup vs baseline: 1.2374x; 1.0543x over previous
//
#include <hip/hip_runtime.h>
#include <hip/hip_bf16.h>

#define HID 64
#define HEADS 4

typedef short s16x8 __attribute__((ext_vector_type(8)));   // 8 bf16 (4 VGPRs)
typedef short s16x4 __attribute__((ext_vector_type(4)));
typedef float f32x4 __attribute__((ext_vector_type(4)));
typedef float f32x2 __attribute__((ext_vector_type(2)));   // candidates for v_pk_*_f32

// flag convention: *flag >= 8  =>  float inputs are fp32; else bf16.
__device__ __forceinline__ float ldw(const void* p, long i, bool f32) {
    return f32 ? ((const float*)p)[i] : (float)((const __hip_bfloat16*)p)[i];
}

__device__ __forceinline__ unsigned short f2b(float f) {   // fp32 -> bf16 bits (RNE, finite)
    unsigned int u = __builtin_bit_cast(unsigned int, f);
    u += 0x7FFF + ((u >> 16) & 1);
    return (unsigned short)(u >> 16);
}
__device__ __forceinline__ float b2f(unsigned short s) {
    unsigned int u = ((unsigned int)s) << 16;
    return __builtin_bit_cast(float, u);
}

#if __has_builtin(__builtin_amdgcn_exp2f)
#define EXP2(x) __builtin_amdgcn_exp2f(x)     // guaranteed single v_exp_f32
#else
#define EXP2(x) exp2f(x)
#endif
#if __has_builtin(__builtin_amdgcn_rcpf)
#define RCP(x) __builtin_amdgcn_rcpf(x)
#else
#define RCP(x) (1.0f / (x))
#endif

// ---------------- dtype probe (16 blocks) + cnt zeroing ----------------
__global__ void detect_kernel(const unsigned short* __restrict__ p, int* __restrict__ flag,
                              int* __restrict__ cnt, int n) {
    int gtid = blockIdx.x * 256 + threadIdx.x;   // 4096 threads x 8 words = 32768
    int hits = 0;
    #pragma unroll
    for (int k = 0; k < 8; k++) {
        unsigned short v = p[gtid + k * 4096];
        if (((v >> 7) & 0xFF) == 0xFF) hits++;   // bf16 NaN/Inf exponent pattern
    }
    if (hits) atomicAdd(flag, hits);
    for (int i = gtid; i < n; i += 4096) cnt[i] = 0;
}

// ---------------- fused prep: A hi/lo planes + all W^T + receiver histogram -------
__global__ __launch_bounds__(256) void prep_hist(
    const void* __restrict__ nodes,
    const void* __restrict__ W0, const void* __restrict__ W1, const void* __restrict__ W2,
    const int* __restrict__ flag,
    unsigned short* __restrict__ nh, unsigned short* __restrict__ nl,
    unsigned short* __restrict__ T0, unsigned short* __restrict__ T1,
    unsigned short* __restrict__ T2,
    const int* __restrict__ recv, int* __restrict__ cnt, long nelem, int E) {
    const bool f32 = (*flag >= 8);
    int g = blockIdx.x * 256 + threadIdx.x;
    int stride = gridDim.x * 256;

    // A -> bf16 hi/lo planes (vec4)
    for (long i = (long)g * 4; i < nelem; i += (long)stride * 4) {
        s16x4 vh, vl;
        if (f32) {
            f32x4 v = *(const f32x4*)((const float*)nodes + i);
            #pragma unroll
            for (int j = 0; j < 4; j++) {
                unsigned short hb = f2b(v[j]);
                vh[j] = (short)hb;
                vl[j] = (short)f2b(v[j] - b2f(hb));
            }
        } else {
            vh = *(const s16x4*)((const unsigned short*)nodes + i);
            vl = (s16x4){0, 0, 0, 0};
        }
        *(s16x4*)(nh + i) = vh;
        *(s16x4*)(nl + i) = vl;
    }
    // W [K,64] -> W^T bf16 [64,K] for all three layers
    for (int i = g; i < 40960; i += stride) {
        const void* W; unsigned short* T; int K, o;
        if (i < 8192)       { W = W0; T = T0; K = 128; o = i; }
        else if (i < 24576) { W = W1; T = T1; K = 256; o = i - 8192; }
        else                { W = W2; T = T2; K = 256; o = i - 24576; }
        int k = o >> 6, n = o & 63;
        T[n * K + k] = f2b(ldw(W, o, f32));
    }
    // receiver histogram
    for (int i = g; i < E; i += stride) atomicAdd(&cnt[recv[i]], 1);
}

// ---------------- single-block scan (exclusive prefix of cnt) ----------------
__global__ __launch_bounds__(1024) void scan_kernel(const int* __restrict__ cnt,
                                                    int* __restrict__ off,
                                                    int* __restrict__ cursor, int n) {
    const int C = (n + 1023) >> 10;          // assume <= 32
    int tid = threadIdx.x;
    int base = tid * C;
    int v[32];
    int tot = 0;
    for (int j = 0; j < C; j++) {
        int idx = base + j;
        int x = (idx < n) ? cnt[idx] : 0;
        v[j] = tot;
        tot += x;
    }
    int lane = tid & 63, w = tid >> 6;
    int incl = tot;
    #pragma unroll
    for (int s = 1; s < 64; s <<= 1) {
        int t = __shfl_up(incl, s, 64);
        if (lane >= s) incl += t;
    }
    __shared__ int wsum[16];
    __shared__ int woff[16];
    if (lane == 63) wsum[w] = incl;
    __syncthreads();
    if (tid < 16) {
        int s = 0;
        for (int i = 0; i < tid; i++) s += wsum[i];
        woff[tid] = s;
    }
    __syncthreads();
    int toff = woff[w] + (incl - tot);
    for (int j = 0; j < C; j++) {
        int idx = base + j;
        if (idx < n) { off[idx] = toff + v[j]; cursor[idx] = toff + v[j]; }
    }
    if (tid == 1023) off[n] = toff + tot;
}

// ---------------- MFMA GEMM body: h = A @ W + b,  A = Ah + Al (bf16 planes) -------
template <int K>
__device__ __forceinline__ void gemm_body(const unsigned short* __restrict__ Ah,
                                          const unsigned short* __restrict__ Al,
                                          const unsigned short* __restrict__ Wt,
                                          const void* __restrict__ bq,
                                          bool f32, bool use_lo,
                                          float* __restrict__ h, int M, int blockId) {
    int lane = threadIdx.x & 63, wv = threadIdx.x >> 6;
    int m16 = lane & 15, quad = lane >> 4;

    int tiles = (M + 15) >> 4;
    int tile = blockId * 4 + wv;
    if (tile >= tiles) return;

    float bias[4];
    #pragma unroll
    for (int t = 0; t < 4; t++) bias[t] = ldw(bq, 16 * t + m16, f32);

    int m0 = tile << 4;
    int row = m0 + m16;
    bool rv = row < M;
    long abase = (long)row * K;
    f32x4 acc[4] = {{0.f,0.f,0.f,0.f},{0.f,0.f,0.f,0.f},{0.f,0.f,0.f,0.f},{0.f,0.f,0.f,0.f}};

    #pragma unroll
    for (int ks = 0; ks < K / 32; ks++) {
        int kb = ks * 32 + quad * 8;
        s16x8 b[4];
        #pragma unroll
        for (int t = 0; t < 4; t++)
            b[t] = *(const s16x8*)(Wt + (16 * t + m16) * K + kb);
        s16x8 ah = rv ? *(const s16x8*)(Ah + abase + kb) : (s16x8){0,0,0,0,0,0,0,0};
        #pragma unroll
        for (int t = 0; t < 4; t++)
            acc[t] = __builtin_amdgcn_mfma_f32_16x16x32_bf16(ah, b[t], acc[t], 0, 0, 0);
        if (use_lo) {
            s16x8 al = rv ? *(const s16x8*)(Al + abase + kb) : (s16x8){0,0,0,0,0,0,0,0};
            #pragma unroll
            for (int t = 0; t < 4; t++)
                acc[t] = __builtin_amdgcn_mfma_f32_16x16x32_bf16(al, b[t], acc[t], 0, 0, 0);
        }
    }

    #pragma unroll
    for (int t = 0; t < 4; t++) {
        #pragma unroll
        for (int r = 0; r < 4; r++) {
            int orow = m0 + quad * 4 + r;        // C/D: col=lane&15, row=quad*4+reg
            if (orow < M) h[(long)orow * 64 + 16 * t + m16] = acc[t][r] + bias[t];
        }
    }
}

template <int K>
__global__ __launch_bounds__(256) void gemm_mfma(const unsigned short* __restrict__ Ah,
                                                 const unsigned short* __restrict__ Al,
                                                 const unsigned short* __restrict__ Wt,
                                                 const void* __restrict__ bq,
                                                 const int* __restrict__ flag,
                                                 float* __restrict__ h, int M, int lo_always) {
    const bool f32 = (*flag >= 8);
    gemm_body<K>(Ah, Al, Wt, bq, f32, lo_always || f32, h, M, blockIdx.x);
}

// ---------------- fused: layer-0 GEMM + edge scatter (independent work) ----------
__global__ __launch_bounds__(256) void gemm0_scatter(
    const unsigned short* __restrict__ Ah, const unsigned short* __restrict__ Al,
    const unsigned short* __restrict__ Wt, const void* __restrict__ bq,
    const int* __restrict__ flag, float* __restrict__ h, int M,
    const int* __restrict__ recv, const int* __restrict__ send,
    int* __restrict__ cursor, int* __restrict__ ssorted, int E, int gemmBlocks) {
    if ((int)blockIdx.x < gemmBlocks) {
        const bool f32 = (*flag >= 8);
        gemm_body<128>(Ah, Al, Wt, bq, f32, f32, h, M, blockIdx.x);
    } else {
        int g = (blockIdx.x - gemmBlocks) * 256 + threadIdx.x;
        int stride = (gridDim.x - gemmBlocks) * 256;
        for (int i = g; i < E; i += stride) {
            int pos = atomicAdd(&cursor[recv[i]], 1);
            ssorted[pos] = send[i];
        }
    }
}

// ---------------- Attention: segment softmax (no-max, exp2-folded) + aggregate ----
// One wave per receiver; lane = hidden dim. Sender ids bulk-loaded 64/chunk into a
// lane register, extracted with v_readlane (wave-uniform index -> sgpr). Gather
// pipeline DEPTH-8 (~270cy coverage ~= L3-miss latency; R7: depth-4 insufficient).
// First ssorted chunk load issued BEFORE the weight/receiver setup to overlap.
// Numerics: logits O(1) (verified R3-R7: absmax = 1 bf16 ulp) -> no-max softmax
// safe; log2(e) folded into weights (leaky(z)*c == leaky(z*c), c>0) -> raw exp2.

__global__ __launch_bounds__(256) void attn_kernel(
    const float* __restrict__ h, const int* __restrict__ off,
    const int* __restrict__ ssorted,
    const void* __restrict__ Wl, const void* __restrict__ bl,
    const int* __restrict__ flag,
    unsigned short* __restrict__ xh, unsigned short* __restrict__ xl,
    void* __restrict__ out, int n, int last) {
    const bool f32 = (*flag >= 8);
    int lane = threadIdx.x & 63;
    int r = __builtin_amdgcn_readfirstlane(blockIdx.x * 4 + (threadIdx.x >> 6));
    if (r >= n) return;

    int start = off[r], end = off[r + 1];    // scalar (r wave-uniform) -- load FIRST
    int idx0 = start + lane;
    int sv = ssorted[(idx0 < end) ? idx0 : ((end > start) ? end - 1 : start)];

    const float LOG2E = 1.44269504f;
    float hr = h[(long)r * HID + lane];
    f32x2 w0p[2], cp[2];
    #pragma unroll
    for (int q = 0; q < 2; q++) {
        #pragma unroll
        for (int c = 0; c < 2; c++) {
            int k = 2 * q + c;
            float w0 = ldw(Wl, k, f32) * LOG2E;
            float w1 = ldw(Wl, HEADS + k, f32) * LOG2E;
            float bb = ldw(bl, k, f32) * LOG2E;
            w0p[q][c] = w0;
            cp[q][c] = fmaf(hr, w1, bb);     // receiver part: loop-invariant
        }
    }

    f32x2 lp[2] = {{0.f, 0.f}, {0.f, 0.f}};
    f32x2 ap[2] = {{0.f, 0.f}, {0.f, 0.f}};
    const float* hbp = h + lane;             // gather base for this lane's dim

    for (int base = start; base < end; base += 64) {
        if (base != start) {                 // first chunk's sv already in flight
            int idx = base + lane;
            sv = ssorted[(idx < end) ? idx : (end - 1)];
        }
        int cnt = min(64, end - base);

        #define LD(j) hbp[(long)__builtin_amdgcn_readlane(sv, (j)) * HID]
        #define STEP(hc) {                                                     \
            float _h = (hc);                                                   \
            _Pragma("unroll")                                                  \
            for (int q = 0; q < 2; q++) {                                      \
                f32x2 t = w0p[q] * _h + cp[q];                                 \
                f32x2 u = t * 0.2f;                                            \
                t.x = fmaxf(t.x, u.x); t.y = fmaxf(t.y, u.y);                  \
                f32x2 pe; pe.x = EXP2(t.x); pe.y = EXP2(t.y);                  \
                lp[q] += pe;                                                   \
                ap[q] += pe * _h;                                              \
            } }

        float q0 = (0 < cnt) ? LD(0) : 0.f;      // depth-8 pipeline prologue
        float q1 = (1 < cnt) ? LD(1) : 0.f;
        float q2 = (2 < cnt) ? LD(2) : 0.f;
        float q3 = (3 < cnt) ? LD(3) : 0.f;
        float q4 = (4 < cnt) ? LD(4) : 0.f;
        float q5 = (5 < cnt) ? LD(5) : 0.f;
        float q6 = (6 < cnt) ? LD(6) : 0.f;
        float q7 = (7 < cnt) ? LD(7) : 0.f;
        int j = 0;
        for (; j + 8 <= cnt; j += 8) {
            float a0 = q0, a1 = q1, a2 = q2, a3 = q3;
            float a4 = q4, a5 = q5, a6 = q6, a7 = q7;
            if (j +  8 < cnt) q0 = LD(j +  8);   // refill: 8 gathers in flight
            if (j +  9 < cnt) q1 = LD(j +  9);
            if (j + 10 < cnt) q2 = LD(j + 10);
            if (j + 11 < cnt) q3 = LD(j + 11);
            if (j + 12 < cnt) q4 = LD(j + 12);
            if (j + 13 < cnt) q5 = LD(j + 13);
            if (j + 14 < cnt) q6 = LD(j + 14);
            if (j + 15 < cnt) q7 = LD(j + 15);
            STEP(a0); STEP(a1); STEP(a2); STEP(a3);
            STEP(a4); STEP(a5); STEP(a6); STEP(a7);
        }
        int remn = cnt - j;                      // 0..7 tail, registers already loaded
        if (remn > 0) STEP(q0);
        if (remn > 1) STEP(q1);
        if (remn > 2) STEP(q2);
        if (remn > 3) STEP(q3);
        if (remn > 4) STEP(q4);
        if (remn > 5) STEP(q5);
        if (remn > 6) STEP(q6);
        #undef LD
        #undef STEP
    }

    bool has = (end > start);
    if (!last) {
        float v[4];
        #pragma unroll
        for (int k = 0; k < HEADS; k++) {
            float a = has ? ap[k >> 1][k & 1] * RCP(lp[k >> 1][k & 1]) : 0.f;
            v[k] = (a > 0.f) ? a : (__expf(a) - 1.f);    // elu
        }
        s16x4 vh, vlo;
        #pragma unroll
        for (int k = 0; k < HEADS; k++) {                // split for next GEMM's A planes
            unsigned short hbk = f2b(v[k]);
            vh[k] = (short)hbk;
            vlo[k] = (short)f2b(v[k] - b2f(hbk));
        }
        long o = (long)r * (HID * HEADS) + lane * HEADS; // reshape: d*HEADS+k
        *(s16x4*)(xh + o) = vh;
        *(s16x4*)(xl + o) = vlo;
    } else {
        float s = 0.f;
        #pragma unroll
        for (int k = 0; k < HEADS; k++)
            s += has ? ap[k >> 1][k & 1] * RCP(lp[k >> 1][k & 1]) : 0.f;
        float a = s * 0.25f;                             // mean over heads
        a = (a > 0.f) ? a : (__expf(a) - 1.f);           // elu
        if (f32) ((float*)out)[(long)r * HID + lane] = a;
        else     ((__hip_bfloat16*)out)[(long)r * HID + lane] = (__hip_bfloat16)a;
    }
}

// ---------------- launch ----------------

extern "C" void kernel_launch(void* const* d_in, const int* in_sizes, int n_in,
                              void* d_out, int out_size, void* d_ws, size_t ws_size,
                              hipStream_t stream) {
    const void* nodes    = d_in[0];
    const int* senders   = (const int*)d_in[1];
    const int* receivers = (const int*)d_in[2];
    const void* Wq0 = d_in[3];  const void* bq0 = d_in[4];
    const void* Wl0 = d_in[5];  const void* bl0 = d_in[6];
    const void* Wq1 = d_in[7];  const void* bq1 = d_in[8];
    const void* Wl1 = d_in[9];  const void* bl1 = d_in[10];
    const void* Wq2 = d_in[11]; const void* bq2 = d_in[12];
    const void* Wl2 = d_in[13]; const void* bl2 = d_in[14];

    int N = in_sizes[0] / 128;
    int E = in_sizes[1];

    char* p = (char*)d_ws;
    int* flag = (int*)p;            p += 64;
    float* h = (float*)p;           p += (size_t)N * 64 * 4;            // 6.4 MB
    unsigned short* nh = (unsigned short*)p;  p += (size_t)N * 128 * 2; // 6.4 MB
    unsigned short* nl = (unsigned short*)p;  p += (size_t)N * 128 * 2;
    unsigned short* xh = (unsigned short*)p;  p += (size_t)N * 256 * 2; // 12.8 MB
    unsigned short* xl = (unsigned short*)p;  p += (size_t)N * 256 * 2;
    unsigned short* Wt0 = (unsigned short*)p; p += 128 * 64 * 2;
    unsigned short* Wt1 = (unsigned short*)p; p += 256 * 64 * 2;
    unsigned short* Wt2 = (unsigned short*)p; p += 256 * 64 * 2;
    int* off = (int*)p;             p += (((size_t)N + 1 + 63) / 64) * 64 * 4;
    int* cnt = (int*)p;             p += (((size_t)N + 63) / 64) * 64 * 4;
    int* cursor = (int*)p;          p += (((size_t)N + 63) / 64) * 64 * 4;
    int* ssorted = (int*)p;         p += (size_t)E * 4;                 // 1.6 MB

    hipMemsetAsync(flag, 0, 4, stream);
    detect_kernel<<<16, 256, 0, stream>>>((const unsigned short*)nodes, flag, cnt, N);

    long nelem = (long)N * 128;
    prep_hist<<<1024, 256, 0, stream>>>(nodes, Wq0, Wq1, Wq2, flag, nh, nl,
                                        Wt0, Wt1, Wt2, receivers, cnt, nelem, E);
    scan_kernel<<<1, 1024, 0, stream>>>(cnt, off, cursor, N);

    int attnGrid = (N + 3) / 4;
    int tiles = (N + 15) / 16;
    int gemmGrid = (tiles + 3) / 4;

    // layer-0 GEMM fused with edge scatter (independent after scan)
    gemm0_scatter<<<gemmGrid * 2, 256, 0, stream>>>(nh, nl, Wt0, bq0, flag, h, N,
                                                    receivers, senders, cursor, ssorted,
                                                    E, gemmGrid);
    attn_kernel<<<attnGrid, 256, 0, stream>>>(h, off, ssorted, Wl0, bl0, flag,
                                              xh, xl, nullptr, N, 0);
    // layer 1
    gemm_mfma<256><<<gemmGrid, 256, 0, stream>>>(xh, xl, Wt1, bq1, flag, h, N, 1);
    attn_kernel<<<attnGrid, 256, 0, stream>>>(h, off, ssorted, Wl1, bl1, flag,
                                              xh, xl, nullptr, N, 0);
    // layer 2 (last: mean over heads + elu)
    gemm_mfma<256><<<gemmGrid, 256, 0, stream>>>(xh, xl, Wt2, bq2, flag, h, N, 1);
    attn_kernel<<<attnGrid, 256, 0, stream>>>(h, off, ssorted, Wl2, bl2, flag,
                                              nullptr, nullptr, d_out, N, 1);
}